// Round 4
// baseline (344.319 us; speedup 1.0000x reference)
//
#include <hip/hip_runtime.h>

typedef __fp16 h2 __attribute__((ext_vector_type(2)));
typedef unsigned int u32;

#define NPTS 1600
#define NCHUNK 10
#define CHUNKJ 160
#define TILE 32
// softmax scale * log2e folded into Q
#define QS (0.35355339059327373f*1.4426950408889634f)
// 1/(sqrt(2)*6)
#define PSCALE 0.11785113019775793f
#define LOG2E 1.4426950408889634f

__device__ __forceinline__ float leaky(float x){ return x >= 0.f ? x : 0.2f*x; }
__device__ __forceinline__ float d4(float4 a, float4 b){ return a.x*b.x + a.y*b.y + a.z*b.z + a.w*b.w; }
__device__ __forceinline__ u32 pkn(float a, float b){ h2 v; v[0]=(__fp16)a; v[1]=(__fp16)b; return __builtin_bit_cast(u32,v); }
__device__ __forceinline__ h2 u2h(u32 u){ return __builtin_bit_cast(h2,u); }
__device__ __forceinline__ float dot2(h2 a, h2 b, float c){ return __builtin_amdgcn_fdot2(a,b,c,false); }
__device__ __forceinline__ u32 rfl(u32 x){ return (u32)__builtin_amdgcn_readfirstlane((int)x); }

// canonical grid spin-barrier: all blocks' prior stores globally visible after return
__device__ __forceinline__ void gbar(u32* ctr, u32 target){
  __threadfence();
  __syncthreads();
  if (threadIdx.x == 0){
    atomicAdd(ctr, 1u);
    while (__hip_atomic_load(ctr, __ATOMIC_ACQUIRE, __HIP_MEMORY_SCOPE_AGENT) < target)
      __builtin_amdgcn_s_sleep(2);
  }
  __syncthreads();
}

// ---------------- K1: input MLP -> barrier -> group-norm -> Q/K/V ----------------
__global__ __launch_bounds__(256) void k_h(
    const float* __restrict__ feat, const float* __restrict__ w1, const float* __restrict__ b1,
    const float* __restrict__ w2, const float* __restrict__ b2,
    const float* __restrict__ conv_w1, const float* __restrict__ conv_b1,
    const float* __restrict__ conv_w2,
    const float* __restrict__ rbf_a, const float* __restrict__ rbf_b,
    const float* __restrict__ rbf_ls, const float* __restrict__ rbf_c,
    const float* __restrict__ g_in, const float* __restrict__ be_in,
    const float* __restrict__ wq, const float* __restrict__ bq,
    const float* __restrict__ wk, const float* __restrict__ bk,
    const float* __restrict__ wv, const float* __restrict__ bv,
    float* __restrict__ Q, float* __restrict__ K, float* __restrict__ V,
    float* __restrict__ bstat1, float* __restrict__ wpk, u32* __restrict__ ctr)
{
  __shared__ float sh[4][64];
  __shared__ float sred[4][8];
  __shared__ float sp[64];
  __shared__ float sst[8];
  int t = threadIdx.x, w = t>>6, c = t&63;
  int i = blockIdx.x*4 + w;

  if (blockIdx.x == 0) {
    u32* wp = (u32*)wpk;
    { // w2 packed f16: 64 rows x 4 u32
      int row = t>>2, q = t&3;
      wp[32 + row*4 + q] = pkn(conv_w2[row*8+2*q], conv_w2[row*8+2*q+1]);
    }
    if (t < 32) { // folded rbf weights: wrg = conv_w1[:,4:8] @ rbf_a
      int cc = t>>2, kq = t&3;
      float a0=0.f, a1=0.f;
      #pragma unroll
      for (int p=0;p<4;p++){ a0 += conv_w1[cc*8+4+p]*rbf_a[p*8+2*kq]; a1 += conv_w1[cc*8+4+p]*rbf_a[p*8+2*kq+1]; }
      wp[cc*4+kq] = pkn(a0,a1);
    } else if (t < 40) { // b1' = conv_b1 + conv_w1[:,4:8] @ rbf_b
      int cc = t-32; float s = conv_b1[cc];
      #pragma unroll
      for (int p=0;p<4;p++) s += conv_w1[cc*8+4+p]*rbf_b[p];
      wpk[288+cc] = s;
    } else if (t == 40) { // rbf quadratic-in-dd coefficients (uniform centers)
      float sig = fmaxf(expf(rbf_ls[0]), 1e-6f);
      float m = -LOG2E/(2.f*sig*sig);
      float c0 = rbf_c[0];
      float dl = rbf_c[1] - rbf_c[0];
      wpk[296] = c0;
      wpk[297] = m;
      wpk[298] = -2.f*m*dl;   // C2
      wpk[299] = m*dl*dl;     // A1
    }
  }

  const float4* f4 = (const float4*)(feat + i*16);
  float4 f0=f4[0], f1v=f4[1], f2v=f4[2], f3v=f4[3];
  const float4* w1r = (const float4*)(w1 + c*16);
  float h1 = b1[c] + d4(f0,w1r[0]) + d4(f1v,w1r[1]) + d4(f2v,w1r[2]) + d4(f3v,w1r[3]);
  h1 = leaky(h1);
  sh[w][c] = h1;
  __syncthreads();
  float hh = b2[c];
  #pragma unroll
  for (int k4=0;k4<16;k4++){
    float4 hv = *(const float4*)&sh[w][k4*4];
    hh += d4(hv, *(const float4*)&w2[c*64 + k4*4]);
  }
  hh = leaky(hh);

  float s = hh, qq = hh*hh;
  s += __shfl_xor(s,1);  qq += __shfl_xor(qq,1);
  s += __shfl_xor(s,2);  qq += __shfl_xor(qq,2);
  s += __shfl_xor(s,4);  qq += __shfl_xor(qq,4);
  s += __shfl_xor(s,8);  qq += __shfl_xor(qq,8);
  if ((c&15)==0){ int g=c>>4; sred[w][g]=s; sred[w][4+g]=qq; }
  __syncthreads();
  if (t<8) bstat1[blockIdx.x*8+t] = sred[0][t]+sred[1][t]+sred[2][t]+sred[3][t];

  gbar(ctr, 400u);   // ---- all h2 + stat partials visible ----

  if (t<64){ int g=t&7; float sacc=0.f;
    for (int m=t>>3; m<400; m+=8)
      sacc += __hip_atomic_load(&bstat1[m*8+g], __ATOMIC_RELAXED, __HIP_MEMORY_SCOPE_AGENT);
    sp[t]=sacc; }
  __syncthreads();
  if (t<8){ float sacc=0.f;
    #pragma unroll
    for (int q=0;q<8;q++) sacc += sp[q*8+t];
    sst[t]=sacc; }
  __syncthreads();
  int g = c>>4;
  const float inv = 1.f/25600.f;
  float mu = sst[g]*inv;
  float var = sst[4+g]*inv - mu*mu;
  float rs = rsqrtf(var + 1e-5f);
  float hn = (hh-mu)*rs*g_in[c] + be_in[c];
  __syncthreads();
  sh[w][c] = hn;
  __syncthreads();
  float q=bq[c], k=bk[c], v=bv[c];
  #pragma unroll
  for (int k4=0;k4<16;k4++){
    float4 hv = *(const float4*)&sh[w][k4*4];
    q += d4(hv, *(const float4*)&wq[c*64+k4*4]);
    k += d4(hv, *(const float4*)&wk[c*64+k4*4]);
    v += d4(hv, *(const float4*)&wv[c*64+k4*4]);
  }
  Q[i*64+c] = q*QS;
  K[i*64+c] = k;
  V[i*64+c] = v;
}

// ---------------- K2: all-pairs kernel (f16 dot2 inner math) ----------------
__global__ __launch_bounds__(256) void k_pair(
  const float* __restrict__ Qm, const float* __restrict__ Km, const float* __restrict__ Vm,
  const float* __restrict__ pts, const float* __restrict__ nuv,
  const float* __restrict__ w1, const float* __restrict__ wpk,
  const float* __restrict__ b2g, float* __restrict__ part)
{
  __shared__ __align__(16) float SM[4928];
  float* sQ  = SM;                 // [16][68] f32
  float* sK  = SM + 1088;          // [32][68] f32
  u32*   sVp = (u32*)(SM + 3264);  // [16][68] u32 (paired f16: rows jl / jl+16)
  u32*   sWX = (u32*)(SM + 4352);  // [16][20] u32 packed per-row Xloc weights
  float* sPt = SM + 4672;          // [32][4]
  float* sNj = SM + 4800;          // [32][4]
  float* sRed = SM;                // [4][16][72] alias (post-loop only)

  int t = threadIdx.x;
  int r = t & 15, jl = t >> 4;
  int bx = blockIdx.x;
  int rb = bx % 100, jc = bx / 100;
  int I0 = rb*16, J0 = jc*CHUNKJ;
  int i = I0 + r;

  { int row = t>>4, col = (t&15)<<2;
    *(float4*)&sQ[row*68+col] = *(const float4*)&Qm[(I0+row)*64 + col]; }
  if (t < 128) { // wx[c][:] = conv_w1[c,0:3] @ nuv[i] ; last = conv_w1[c,3]
    int r2 = t>>3, cc = t&7, ib = (I0+r2)*9;
    float a0=w1[cc*8], a1=w1[cc*8+1], a2=w1[cc*8+2];
    float x = a0*nuv[ib+0] + a1*nuv[ib+3] + a2*nuv[ib+6];
    float y = a0*nuv[ib+1] + a1*nuv[ib+4] + a2*nuv[ib+7];
    float z = a0*nuv[ib+2] + a1*nuv[ib+5] + a2*nuv[ib+8];
    sWX[r2*20+cc*2+0] = pkn(x,y);
    sWX[r2*20+cc*2+1] = pkn(z, w1[cc*8+3]);
  }
  __syncthreads();
  u32 wxp[16];
  #pragma unroll
  for (int q2=0;q2<4;q2++) *(uint4*)&wxp[q2*4] = *(const uint4*)&sWX[r*20+q2*4];

  const u32* wp = (const u32*)wpk;
  h2 wr[8][4];
  #pragma unroll
  for (int cc=0;cc<8;cc++)
    #pragma unroll
    for (int q2=0;q2<4;q2++) wr[cc][q2] = u2h(rfl(wp[cc*4+q2]));
  const u32* w2p = wp + 32;
  const float* b1p = wpk + 288;
  float c0  = wpk[296];
  float mco = wpk[297];
  float C2  = wpk[298];
  float A1  = wpk[299];

  float pix = pts[i*3+0]*PSCALE, piy = pts[i*3+1]*PSCALE, piz = pts[i*3+2]*PSCALE;
  float nix = nuv[i*9+0], niy = nuv[i*9+1], niz = nuv[i*9+2];

  float acc[64];
  #pragma unroll
  for (int o=0;o<64;o++) acc[o] = 0.f;
  float lh[8];
  #pragma unroll
  for (int h=0;h<8;h++) lh[h] = 0.f;

  #pragma unroll 1
  for (int tb=0; tb<CHUNKJ; tb+=TILE) {
    int jbase = J0 + tb;
    __syncthreads();
    #pragma unroll
    for (int q2=0;q2<2;q2++) {
      int idx = t + q2*256;
      int row = idx >> 4, col = (idx & 15) << 2;
      *(float4*)&sK[row*68+col] = *(const float4*)&Km[(jbase+row)*64+col];
    }
    { int row = t>>4, col = (t&15)<<2;
      float4 a = *(const float4*)&Vm[(jbase+row)*64+col];
      float4 b = *(const float4*)&Vm[(jbase+16+row)*64+col];
      uint4 p; p.x=pkn(a.x,b.x); p.y=pkn(a.y,b.y); p.z=pkn(a.z,b.z); p.w=pkn(a.w,b.w);
      *(uint4*)&sVp[row*68+col] = p;
    }
    if (t < TILE) {
      int j = jbase + t;
      sPt[t*4+0]=pts[j*3+0]*PSCALE; sPt[t*4+1]=pts[j*3+1]*PSCALE; sPt[t*4+2]=pts[j*3+2]*PSCALE;
      sNj[t*4+0]=nuv[j*9+0]; sNj[t*4+1]=nuv[j*9+1]; sNj[t*4+2]=nuv[j*9+2];
    }
    __syncthreads();

    h2 F1p[2][4];
    float Wv[2];
    #pragma unroll
    for (int jj=0;jj<2;jj++) {
      int jloc = jl + (jj<<4);
      float dx = sPt[jloc*4+0]-pix, dy = sPt[jloc*4+1]-piy, dz = sPt[jloc*4+2]-piz;
      float ndot = nix*sNj[jloc*4+0] + niy*sNj[jloc*4+1] + niz*sNj[jloc*4+2];
      float d2r = dx*dx + dy*dy + dz*dz;
      float wf = 2.f - ndot;
      float d2 = d2r*wf*wf;
      float tp = fmaf(d2, 0.3333333333333333f, 1.f);
      Wv[jj] = __builtin_amdgcn_rcpf(tp*tp*tp);     // (1+d2/3)^-3
      float dd = __builtin_amdgcn_sqrtf(d2);
      float g0 = dd - c0;
      float s2 = mco*g0*g0;
      float uu = C2*g0;
      float R[8];
      #pragma unroll
      for (int k=0;k<8;k++){
        float kf = (float)k, k2f = (float)(k*k);
        R[k] = __builtin_amdgcn_exp2f(fmaf(kf, uu, fmaf(k2f, A1, s2)));
      }
      h2 xv0; xv0[0]=(__fp16)dx; xv0[1]=(__fp16)dy;
      h2 xv1; xv1[0]=(__fp16)dz; xv1[1]=(__fp16)ndot;
      h2 r01=__builtin_amdgcn_cvt_pkrtz(R[0],R[1]);
      h2 r23=__builtin_amdgcn_cvt_pkrtz(R[2],R[3]);
      h2 r45=__builtin_amdgcn_cvt_pkrtz(R[4],R[5]);
      h2 r67=__builtin_amdgcn_cvt_pkrtz(R[6],R[7]);
      float F1f[8];
      #pragma unroll
      for (int cc=0;cc<8;cc++){
        float f = dot2(r67, wr[cc][3], b1p[cc]);
        f = dot2(r45, wr[cc][2], f);
        f = dot2(r23, wr[cc][1], f);
        f = dot2(r01, wr[cc][0], f);
        f = dot2(u2h(wxp[cc*2+1]), xv1, f);
        f = dot2(u2h(wxp[cc*2+0]), xv0, f);
        F1f[cc] = fmaxf(f, 0.f);
      }
      F1p[jj][0]=__builtin_amdgcn_cvt_pkrtz(F1f[0],F1f[1]);
      F1p[jj][1]=__builtin_amdgcn_cvt_pkrtz(F1f[2],F1f[3]);
      F1p[jj][2]=__builtin_amdgcn_cvt_pkrtz(F1f[4],F1f[5]);
      F1p[jj][3]=__builtin_amdgcn_cvt_pkrtz(F1f[6],F1f[7]);
    }

    #pragma unroll
    for (int h=0;h<8;h++) {
      float4 q0 = *(const float4*)&sQ[r*68+h*8];
      float4 q1 = *(const float4*)&sQ[r*68+h*8+4];
      float4 ka0 = *(const float4*)&sK[jl*68+h*8];
      float4 ka1 = *(const float4*)&sK[jl*68+h*8+4];
      float4 kb0 = *(const float4*)&sK[(jl+16)*68+h*8];
      float4 kb1 = *(const float4*)&sK[(jl+16)*68+h*8+4];
      float S0 = d4(q0,ka0) + d4(q1,ka1);   // exp2 domain (QS folded)
      float S1 = d4(q0,kb0) + d4(q1,kb1);
      float e0 = __builtin_amdgcn_exp2f(S0);
      float e1 = __builtin_amdgcn_exp2f(S1);
      lh[h] += e0 + e1;
      h2 ewp; ewp[0]=(__fp16)(e0*Wv[0]); ewp[1]=(__fp16)(e1*Wv[1]);
      uint4 vpA = *(const uint4*)&sVp[jl*68+h*8];
      uint4 vpB = *(const uint4*)&sVp[jl*68+h*8+4];
      u32 vparr[8] = {vpA.x,vpA.y,vpA.z,vpA.w,vpB.x,vpB.y,vpB.z,vpB.w};
      #pragma unroll
      for (int cc=0;cc<8;cc++){
        int rw = h*8+cc;
        h2 w0=u2h(w2p[rw*4+0]), w1h=u2h(w2p[rw*4+1]), w2h=u2h(w2p[rw*4+2]), w3h=u2h(w2p[rw*4+3]);
        float b2v = b2g[rw];
        float fh0 = dot2(F1p[0][0],w0, dot2(F1p[0][1],w1h, dot2(F1p[0][2],w2h, dot2(F1p[0][3],w3h, b2v))));
        float fh1 = dot2(F1p[1][0],w0, dot2(F1p[1][1],w1h, dot2(F1p[1][2],w2h, dot2(F1p[1][3],w3h, b2v))));
        h2 fhp = __builtin_amdgcn_cvt_pkrtz(fmaxf(fh0,0.f), fmaxf(fh1,0.f));
        h2 ev = u2h(vparr[cc]) * ewp;
        acc[rw] = dot2(fhp, ev, acc[rw]);
      }
    }
  }

  #pragma unroll
  for (int o=0;o<64;o++){ acc[o] += __shfl_xor(acc[o],16); acc[o] += __shfl_xor(acc[o],32); }
  #pragma unroll
  for (int h=0;h<8;h++){ lh[h] += __shfl_xor(lh[h],16); lh[h] += __shfl_xor(lh[h],32); }
  __syncthreads();
  int wv = t >> 6, lane = t & 63;
  if (lane < 16) {
    #pragma unroll
    for (int o=0;o<64;o++) sRed[(wv*16+lane)*72+o] = acc[o];
    #pragma unroll
    for (int h=0;h<8;h++) sRed[(wv*16+lane)*72+64+h] = lh[h];
  }
  __syncthreads();
  for (int v2 = t; v2 < 16*72; v2 += 256) {
    int rr = v2/72, o = v2 - rr*72;
    part[(jc*NPTS + I0 + rr)*72 + o] =
      sRed[(0*16+rr)*72+o] + sRed[(1*16+rr)*72+o] + sRed[(2*16+rr)*72+o] + sRed[(3*16+rr)*72+o];
  }
}

// ---------------- K3: merge partials -> MLP -> barrier -> group-norm + residual ----------------
__global__ __launch_bounds__(256) void k_tail(
  const float* __restrict__ part, const float* __restrict__ w_o1, const float* __restrict__ b_o1,
  const float* __restrict__ w_o2, const float* __restrict__ b_o2,
  const float* __restrict__ g_out, const float* __restrict__ be_out,
  const float* __restrict__ feat, const float* __restrict__ w_res, const float* __restrict__ b_res,
  float* __restrict__ bstat2, u32* __restrict__ ctr, float* __restrict__ out)
{
  __shared__ float sh[4][64];
  __shared__ float sred[4][8];
  __shared__ float sp[64];
  __shared__ float sst[8];
  int t = threadIdx.x, w = t>>6, c = t&63;
  int i = blockIdx.x*4 + w;
  int h = c>>3;
  float a = 0.f, L = 0.f;
  #pragma unroll
  for (int jc=0;jc<NCHUNK;jc++){
    const float* p = part + (jc*NPTS + i)*72;
    a += p[c]; L += p[64+h];
  }
  float agg = a / L;
  sh[w][c] = agg; __syncthreads();
  float o1 = b_o1[c];
  #pragma unroll
  for (int k4=0;k4<16;k4++){
    float4 hv = *(const float4*)&sh[w][k4*4];
    o1 += d4(hv, *(const float4*)&w_o1[c*64+k4*4]);
  }
  o1 = leaky(o1);
  __syncthreads();
  sh[w][c] = o1; __syncthreads();
  float o2 = b_o2[c];
  #pragma unroll
  for (int k4=0;k4<16;k4++){
    float4 hv = *(const float4*)&sh[w][k4*4];
    o2 += d4(hv, *(const float4*)&w_o2[c*64+k4*4]);
  }
  o2 = leaky(o2);

  float s = o2, qq = o2*o2;
  s += __shfl_xor(s,1);  qq += __shfl_xor(qq,1);
  s += __shfl_xor(s,2);  qq += __shfl_xor(qq,2);
  s += __shfl_xor(s,4);  qq += __shfl_xor(qq,4);
  s += __shfl_xor(s,8);  qq += __shfl_xor(qq,8);
  if ((c&15)==0){ int g=c>>4; sred[w][g]=s; sred[w][4+g]=qq; }
  __syncthreads();
  if (t<8) bstat2[blockIdx.x*8+t] = sred[0][t]+sred[1][t]+sred[2][t]+sred[3][t];

  gbar(ctr, 400u);   // ---- all o2 stat partials visible ----

  if (t<64){ int g=t&7; float sacc=0.f;
    for (int m=t>>3; m<400; m+=8)
      sacc += __hip_atomic_load(&bstat2[m*8+g], __ATOMIC_RELAXED, __HIP_MEMORY_SCOPE_AGENT);
    sp[t]=sacc; }
  __syncthreads();
  if (t<8){ float sacc=0.f;
    #pragma unroll
    for (int q=0;q<8;q++) sacc += sp[q*8+t];
    sst[t]=sacc; }
  __syncthreads();
  int g = c>>4;
  const float inv = 1.f/25600.f;
  float mu = sst[g]*inv;
  float var = sst[4+g]*inv - mu*mu;
  float rs = rsqrtf(var + 1e-5f);
  float on = (o2-mu)*rs*g_out[c] + be_out[c];
  const float4* f4 = (const float4*)(feat + i*16);
  const float4* wrr = (const float4*)(w_res + c*16);
  float res = b_res[c] + d4(f4[0],wrr[0]) + d4(f4[1],wrr[1]) + d4(f4[2],wrr[2]) + d4(f4[3],wrr[3]);
  out[i*64+c] = on + res;
}

extern "C" void kernel_launch(void* const* d_in, const int* in_sizes, int n_in,
                              void* d_out, int out_size, void* d_ws, size_t ws_size,
                              hipStream_t stream) {
  const float* points  = (const float*)d_in[0];
  const float* nuv     = (const float*)d_in[1];
  const float* feat    = (const float*)d_in[2];
  const float* w_in1   = (const float*)d_in[3];
  const float* b_in1   = (const float*)d_in[4];
  const float* w_in2   = (const float*)d_in[5];
  const float* b_in2   = (const float*)d_in[6];
  const float* g_in    = (const float*)d_in[7];
  const float* be_in   = (const float*)d_in[8];
  const float* wq      = (const float*)d_in[9];
  const float* bq      = (const float*)d_in[10];
  const float* wk      = (const float*)d_in[11];
  const float* bk      = (const float*)d_in[12];
  const float* wv      = (const float*)d_in[13];
  const float* bv      = (const float*)d_in[14];
  const float* conv_w1 = (const float*)d_in[15];
  const float* conv_b1 = (const float*)d_in[16];
  const float* conv_w2 = (const float*)d_in[17];
  const float* conv_b2 = (const float*)d_in[18];
  const float* rbf_ls  = (const float*)d_in[19];
  const float* rbf_a   = (const float*)d_in[20];
  const float* rbf_b   = (const float*)d_in[21];
  const float* rbf_c   = (const float*)d_in[22];
  const float* w_o1    = (const float*)d_in[23];
  const float* b_o1    = (const float*)d_in[24];
  const float* w_o2    = (const float*)d_in[25];
  const float* b_o2    = (const float*)d_in[26];
  const float* g_out   = (const float*)d_in[27];
  const float* be_out  = (const float*)d_in[28];
  const float* w_res   = (const float*)d_in[29];
  const float* b_res   = (const float*)d_in[30];

  float* ws     = (float*)d_ws;
  float* Qb     = ws;                 // 102400
  float* Kb     = ws + 102400;        // 102400
  float* Vb     = ws + 204800;        // 102400
  float* bstat1 = ws + 307200;        // 3200
  float* bstat2 = ws + 310400;        // 3200
  float* wpk    = ws + 313600;        // 320
  u32*   ctr    = (u32*)(ws + 313920);// 2 counters (16B reserved)
  float* part   = ws + 313924;        // 10*1600*72 = 1152000
  float* out    = (float*)d_out;

  hipMemsetAsync(ctr, 0, 16, stream);
  k_h<<<400, 256, 0, stream>>>(feat, w_in1, b_in1, w_in2, b_in2,
                               conv_w1, conv_b1, conv_w2, rbf_a, rbf_b, rbf_ls, rbf_c,
                               g_in, be_in, wq, bq, wk, bk, wv, bv,
                               Qb, Kb, Vb, bstat1, wpk, ctr);
  k_pair<<<1000, 256, 0, stream>>>(Qb, Kb, Vb, points, nuv, conv_w1, wpk, conv_b2, part);
  k_tail<<<400, 256, 0, stream>>>(part, w_o1, b_o1, w_o2, b_o2, g_out, be_out,
                                  feat, w_res, b_res, bstat2, ctr+1, out);
}

// Round 5
// 253.252 us; speedup vs baseline: 1.3596x; 1.3596x over previous
//
#include <hip/hip_runtime.h>

typedef __fp16 h2 __attribute__((ext_vector_type(2)));
typedef unsigned int u32;

#define NPTS 1600
#define NCHUNK 10
#define CHUNKJ 160
#define TILE 32
// softmax scale * log2e folded into Q
#define QS (0.35355339059327373f*1.4426950408889634f)
// 1/(sqrt(2)*6)
#define PSCALE 0.11785113019775793f
#define LOG2E 1.4426950408889634f

__device__ __forceinline__ float leaky(float x){ return x >= 0.f ? x : 0.2f*x; }
__device__ __forceinline__ float d4(float4 a, float4 b){ return a.x*b.x + a.y*b.y + a.z*b.z + a.w*b.w; }
__device__ __forceinline__ u32 pkn(float a, float b){ h2 v; v[0]=(__fp16)a; v[1]=(__fp16)b; return __builtin_bit_cast(u32,v); }
__device__ __forceinline__ h2 u2h(u32 u){ return __builtin_bit_cast(h2,u); }
__device__ __forceinline__ float dot2(h2 a, h2 b, float c){ return __builtin_amdgcn_fdot2(a,b,c,false); }
__device__ __forceinline__ u32 rfl(u32 x){ return (u32)__builtin_amdgcn_readfirstlane((int)x); }

// ---------------- K1: input MLP + group stats partials + weight packing ----------------
__global__ __launch_bounds__(256) void k_in(
    const float* __restrict__ feat, const float* __restrict__ w1, const float* __restrict__ b1,
    const float* __restrict__ w2, const float* __restrict__ b2,
    const float* __restrict__ conv_w1, const float* __restrict__ conv_b1,
    const float* __restrict__ conv_w2,
    const float* __restrict__ rbf_a, const float* __restrict__ rbf_b,
    const float* __restrict__ rbf_ls, const float* __restrict__ rbf_c,
    float* __restrict__ h2out, float* __restrict__ bstat1, float* __restrict__ wpk)
{
  __shared__ float sh[4][64];
  __shared__ float sred[4][8];
  int t = threadIdx.x, w = t>>6, c = t&63;
  int i = blockIdx.x*4 + w;

  if (blockIdx.x == 0) {
    u32* wp = (u32*)wpk;
    { // w2 packed f16: 64 rows x 4 u32
      int row = t>>2, q = t&3;
      wp[32 + row*4 + q] = pkn(conv_w2[row*8+2*q], conv_w2[row*8+2*q+1]);
    }
    if (t < 32) { // folded rbf weights: wrg = conv_w1[:,4:8] @ rbf_a
      int cc = t>>2, kq = t&3;
      float a0=0.f, a1=0.f;
      #pragma unroll
      for (int p=0;p<4;p++){ a0 += conv_w1[cc*8+4+p]*rbf_a[p*8+2*kq]; a1 += conv_w1[cc*8+4+p]*rbf_a[p*8+2*kq+1]; }
      wp[cc*4+kq] = pkn(a0,a1);
    } else if (t < 40) { // b1' = conv_b1 + conv_w1[:,4:8] @ rbf_b
      int cc = t-32; float s = conv_b1[cc];
      #pragma unroll
      for (int p=0;p<4;p++) s += conv_w1[cc*8+4+p]*rbf_b[p];
      wpk[288+cc] = s;
    } else if (t == 40) { // rbf quadratic-in-dd coefficients (uniform centers)
      float sig = fmaxf(expf(rbf_ls[0]), 1e-6f);
      float m = -LOG2E/(2.f*sig*sig);
      float c0 = rbf_c[0];
      float dl = rbf_c[1] - rbf_c[0];
      wpk[296] = c0;
      wpk[297] = m;
      wpk[298] = -2.f*m*dl;   // C2
      wpk[299] = m*dl*dl;     // A1
    }
  }

  const float4* f4 = (const float4*)(feat + i*16);
  float4 f0=f4[0], f1v=f4[1], f2v=f4[2], f3v=f4[3];
  const float4* w1r = (const float4*)(w1 + c*16);
  float h1 = b1[c] + d4(f0,w1r[0]) + d4(f1v,w1r[1]) + d4(f2v,w1r[2]) + d4(f3v,w1r[3]);
  h1 = leaky(h1);
  sh[w][c] = h1;
  __syncthreads();
  float hh = b2[c];
  #pragma unroll
  for (int k4=0;k4<16;k4++){
    float4 hv = *(const float4*)&sh[w][k4*4];
    hh += d4(hv, *(const float4*)&w2[c*64 + k4*4]);
  }
  hh = leaky(hh);
  h2out[i*64+c] = hh;

  float s = hh, qq = hh*hh;
  s += __shfl_xor(s,1);  qq += __shfl_xor(qq,1);
  s += __shfl_xor(s,2);  qq += __shfl_xor(qq,2);
  s += __shfl_xor(s,4);  qq += __shfl_xor(qq,4);
  s += __shfl_xor(s,8);  qq += __shfl_xor(qq,8);
  if ((c&15)==0){ int g=c>>4; sred[w][g]=s; sred[w][4+g]=qq; }
  __syncthreads();
  if (t<8) bstat1[blockIdx.x*8+t] = sred[0][t]+sred[1][t]+sred[2][t]+sred[3][t];
}

// ---------------- K2: reduce stats, group-norm, Q/K/V projections ----------------
__global__ __launch_bounds__(256) void k_qkv(
  const float* __restrict__ h2b, const float* __restrict__ bstat1,
  const float* __restrict__ g_in, const float* __restrict__ be_in,
  const float* __restrict__ wq, const float* __restrict__ bq,
  const float* __restrict__ wk, const float* __restrict__ bk,
  const float* __restrict__ wv, const float* __restrict__ bv,
  float* __restrict__ Q, float* __restrict__ K, float* __restrict__ V)
{
  __shared__ float sh[4][64];
  __shared__ float sp[64];
  __shared__ float sst[8];
  int t=threadIdx.x, w=t>>6, c=t&63;
  int i = blockIdx.x*4 + w;
  if (t<64){ int g=t&7; float s=0.f;
    for (int m=t>>3; m<400; m+=8) s += bstat1[m*8+g];
    sp[t]=s; }
  __syncthreads();
  if (t<8){ float s=0.f;
    #pragma unroll
    for (int q=0;q<8;q++) s += sp[q*8+t];
    sst[t]=s; }
  __syncthreads();
  int g = c>>4;
  const float inv = 1.f/25600.f;
  float mu = sst[g]*inv;
  float var = sst[4+g]*inv - mu*mu;
  float rs = rsqrtf(var + 1e-5f);
  float hn = (h2b[i*64+c]-mu)*rs*g_in[c] + be_in[c];
  sh[w][c] = hn;
  __syncthreads();
  float q=bq[c], k=bk[c], v=bv[c];
  #pragma unroll
  for (int k4=0;k4<16;k4++){
    float4 hv = *(const float4*)&sh[w][k4*4];
    q += d4(hv, *(const float4*)&wq[c*64+k4*4]);
    k += d4(hv, *(const float4*)&wk[c*64+k4*4]);
    v += d4(hv, *(const float4*)&wv[c*64+k4*4]);
  }
  Q[i*64+c] = q*QS;
  K[i*64+c] = k;
  V[i*64+c] = v;
}

// ---------------- K3: all-pairs kernel (f16 dot2 inner math) ----------------
__global__ __launch_bounds__(256) void k_pair(
  const float* __restrict__ Qm, const float* __restrict__ Km, const float* __restrict__ Vm,
  const float* __restrict__ pts, const float* __restrict__ nuv,
  const float* __restrict__ w1, const float* __restrict__ wpk,
  const float* __restrict__ b2g, float* __restrict__ part)
{
  __shared__ __align__(16) float SM[4928];
  float* sQ  = SM;                 // [16][68] f32
  float* sK  = SM + 1088;          // [32][68] f32
  u32*   sVp = (u32*)(SM + 3264);  // [16][68] u32 (paired f16: rows jl / jl+16)
  u32*   sWX = (u32*)(SM + 4352);  // [16][20] u32 packed per-row Xloc weights
  float* sPt = SM + 4672;          // [32][4]
  float* sNj = SM + 4800;          // [32][4]
  float* sRed = SM;                // [4][16][72] alias (post-loop only)

  int t = threadIdx.x;
  int r = t & 15, jl = t >> 4;
  int bx = blockIdx.x;
  int rb = bx % 100, jc = bx / 100;
  int I0 = rb*16, J0 = jc*CHUNKJ;
  int i = I0 + r;

  { int row = t>>4, col = (t&15)<<2;
    *(float4*)&sQ[row*68+col] = *(const float4*)&Qm[(I0+row)*64 + col]; }
  if (t < 128) { // wx[c][:] = conv_w1[c,0:3] @ nuv[i] ; last = conv_w1[c,3]
    int r2 = t>>3, cc = t&7, ib = (I0+r2)*9;
    float a0=w1[cc*8], a1=w1[cc*8+1], a2=w1[cc*8+2];
    float x = a0*nuv[ib+0] + a1*nuv[ib+3] + a2*nuv[ib+6];
    float y = a0*nuv[ib+1] + a1*nuv[ib+4] + a2*nuv[ib+7];
    float z = a0*nuv[ib+2] + a1*nuv[ib+5] + a2*nuv[ib+8];
    sWX[r2*20+cc*2+0] = pkn(x,y);
    sWX[r2*20+cc*2+1] = pkn(z, w1[cc*8+3]);
  }
  __syncthreads();
  u32 wxp[16];
  #pragma unroll
  for (int q2=0;q2<4;q2++) *(uint4*)&wxp[q2*4] = *(const uint4*)&sWX[r*20+q2*4];

  const u32* wp = (const u32*)wpk;
  h2 wr[8][4];
  #pragma unroll
  for (int cc=0;cc<8;cc++)
    #pragma unroll
    for (int q2=0;q2<4;q2++) wr[cc][q2] = u2h(rfl(wp[cc*4+q2]));
  const u32* w2p = wp + 32;
  const float* b1p = wpk + 288;
  float c0  = wpk[296];
  float mco = wpk[297];
  float C2  = wpk[298];
  float A1  = wpk[299];

  float pix = pts[i*3+0]*PSCALE, piy = pts[i*3+1]*PSCALE, piz = pts[i*3+2]*PSCALE;
  float nix = nuv[i*9+0], niy = nuv[i*9+1], niz = nuv[i*9+2];

  float acc[64];
  #pragma unroll
  for (int o=0;o<64;o++) acc[o] = 0.f;
  float lh[8];
  #pragma unroll
  for (int h=0;h<8;h++) lh[h] = 0.f;

  #pragma unroll 1
  for (int tb=0; tb<CHUNKJ; tb+=TILE) {
    int jbase = J0 + tb;
    __syncthreads();
    #pragma unroll
    for (int q2=0;q2<2;q2++) {
      int idx = t + q2*256;
      int row = idx >> 4, col = (idx & 15) << 2;
      *(float4*)&sK[row*68+col] = *(const float4*)&Km[(jbase+row)*64+col];
    }
    { int row = t>>4, col = (t&15)<<2;
      float4 a = *(const float4*)&Vm[(jbase+row)*64+col];
      float4 b = *(const float4*)&Vm[(jbase+16+row)*64+col];
      uint4 p; p.x=pkn(a.x,b.x); p.y=pkn(a.y,b.y); p.z=pkn(a.z,b.z); p.w=pkn(a.w,b.w);
      *(uint4*)&sVp[row*68+col] = p;
    }
    if (t < TILE) {
      int j = jbase + t;
      sPt[t*4+0]=pts[j*3+0]*PSCALE; sPt[t*4+1]=pts[j*3+1]*PSCALE; sPt[t*4+2]=pts[j*3+2]*PSCALE;
      sNj[t*4+0]=nuv[j*9+0]; sNj[t*4+1]=nuv[j*9+1]; sNj[t*4+2]=nuv[j*9+2];
    }
    __syncthreads();

    h2 F1p[2][4];
    float Wv[2];
    #pragma unroll
    for (int jj=0;jj<2;jj++) {
      int jloc = jl + (jj<<4);
      float dx = sPt[jloc*4+0]-pix, dy = sPt[jloc*4+1]-piy, dz = sPt[jloc*4+2]-piz;
      float ndot = nix*sNj[jloc*4+0] + niy*sNj[jloc*4+1] + niz*sNj[jloc*4+2];
      float d2r = dx*dx + dy*dy + dz*dz;
      float wf = 2.f - ndot;
      float d2 = d2r*wf*wf;
      float tp = fmaf(d2, 0.3333333333333333f, 1.f);
      Wv[jj] = __builtin_amdgcn_rcpf(tp*tp*tp);     // (1+d2/3)^-3
      float dd = __builtin_amdgcn_sqrtf(d2);
      float g0 = dd - c0;
      float s2 = mco*g0*g0;
      float uu = C2*g0;
      float R[8];
      #pragma unroll
      for (int k=0;k<8;k++){
        float kf = (float)k, k2f = (float)(k*k);
        R[k] = __builtin_amdgcn_exp2f(fmaf(kf, uu, fmaf(k2f, A1, s2)));
      }
      h2 xv0; xv0[0]=(__fp16)dx; xv0[1]=(__fp16)dy;
      h2 xv1; xv1[0]=(__fp16)dz; xv1[1]=(__fp16)ndot;
      h2 r01=__builtin_amdgcn_cvt_pkrtz(R[0],R[1]);
      h2 r23=__builtin_amdgcn_cvt_pkrtz(R[2],R[3]);
      h2 r45=__builtin_amdgcn_cvt_pkrtz(R[4],R[5]);
      h2 r67=__builtin_amdgcn_cvt_pkrtz(R[6],R[7]);
      float F1f[8];
      #pragma unroll
      for (int cc=0;cc<8;cc++){
        float f = dot2(r67, wr[cc][3], b1p[cc]);
        f = dot2(r45, wr[cc][2], f);
        f = dot2(r23, wr[cc][1], f);
        f = dot2(r01, wr[cc][0], f);
        f = dot2(u2h(wxp[cc*2+1]), xv1, f);
        f = dot2(u2h(wxp[cc*2+0]), xv0, f);
        F1f[cc] = fmaxf(f, 0.f);
      }
      F1p[jj][0]=__builtin_amdgcn_cvt_pkrtz(F1f[0],F1f[1]);
      F1p[jj][1]=__builtin_amdgcn_cvt_pkrtz(F1f[2],F1f[3]);
      F1p[jj][2]=__builtin_amdgcn_cvt_pkrtz(F1f[4],F1f[5]);
      F1p[jj][3]=__builtin_amdgcn_cvt_pkrtz(F1f[6],F1f[7]);
    }

    #pragma unroll
    for (int h=0;h<8;h++) {
      float4 q0 = *(const float4*)&sQ[r*68+h*8];
      float4 q1 = *(const float4*)&sQ[r*68+h*8+4];
      float4 ka0 = *(const float4*)&sK[jl*68+h*8];
      float4 ka1 = *(const float4*)&sK[jl*68+h*8+4];
      float4 kb0 = *(const float4*)&sK[(jl+16)*68+h*8];
      float4 kb1 = *(const float4*)&sK[(jl+16)*68+h*8+4];
      float S0 = d4(q0,ka0) + d4(q1,ka1);   // exp2 domain (QS folded)
      float S1 = d4(q0,kb0) + d4(q1,kb1);
      float e0 = __builtin_amdgcn_exp2f(S0);
      float e1 = __builtin_amdgcn_exp2f(S1);
      lh[h] += e0 + e1;
      h2 ewp; ewp[0]=(__fp16)(e0*Wv[0]); ewp[1]=(__fp16)(e1*Wv[1]);
      uint4 vpA = *(const uint4*)&sVp[jl*68+h*8];
      uint4 vpB = *(const uint4*)&sVp[jl*68+h*8+4];
      u32 vparr[8] = {vpA.x,vpA.y,vpA.z,vpA.w,vpB.x,vpB.y,vpB.z,vpB.w};
      #pragma unroll
      for (int cc=0;cc<8;cc++){
        int rw = h*8+cc;
        h2 w0=u2h(w2p[rw*4+0]), w1h=u2h(w2p[rw*4+1]), w2h=u2h(w2p[rw*4+2]), w3h=u2h(w2p[rw*4+3]);
        float b2v = b2g[rw];
        float fh0 = dot2(F1p[0][0],w0, dot2(F1p[0][1],w1h, dot2(F1p[0][2],w2h, dot2(F1p[0][3],w3h, b2v))));
        float fh1 = dot2(F1p[1][0],w0, dot2(F1p[1][1],w1h, dot2(F1p[1][2],w2h, dot2(F1p[1][3],w3h, b2v))));
        h2 fhp = __builtin_amdgcn_cvt_pkrtz(fmaxf(fh0,0.f), fmaxf(fh1,0.f));
        h2 ev = u2h(vparr[cc]) * ewp;
        acc[rw] = dot2(fhp, ev, acc[rw]);
      }
    }
  }

  #pragma unroll
  for (int o=0;o<64;o++){ acc[o] += __shfl_xor(acc[o],16); acc[o] += __shfl_xor(acc[o],32); }
  #pragma unroll
  for (int h=0;h<8;h++){ lh[h] += __shfl_xor(lh[h],16); lh[h] += __shfl_xor(lh[h],32); }
  __syncthreads();
  int wv = t >> 6, lane = t & 63;
  if (lane < 16) {
    #pragma unroll
    for (int o=0;o<64;o++) sRed[(wv*16+lane)*72+o] = acc[o];
    #pragma unroll
    for (int h=0;h<8;h++) sRed[(wv*16+lane)*72+64+h] = lh[h];
  }
  __syncthreads();
  for (int v2 = t; v2 < 16*72; v2 += 256) {
    int rr = v2/72, o = v2 - rr*72;
    part[(jc*NPTS + I0 + rr)*72 + o] =
      sRed[(0*16+rr)*72+o] + sRed[(1*16+rr)*72+o] + sRed[(2*16+rr)*72+o] + sRed[(3*16+rr)*72+o];
  }
}

// ---------------- K4: merge chunk partials, divide, output MLP, out-stat partials ----------------
__global__ __launch_bounds__(256) void k_agg(
  const float* __restrict__ part, const float* __restrict__ w_o1, const float* __restrict__ b_o1,
  const float* __restrict__ w_o2, const float* __restrict__ b_o2,
  float* __restrict__ o2b, float* __restrict__ bstat2)
{
  __shared__ float sh[4][64];
  __shared__ float sred[4][8];
  int t = threadIdx.x, w = t>>6, c = t&63;
  int i = blockIdx.x*4 + w;
  int h = c>>3;
  float a = 0.f, L = 0.f;
  #pragma unroll
  for (int jc=0;jc<NCHUNK;jc++){
    const float* p = part + (jc*NPTS + i)*72;
    a += p[c]; L += p[64+h];
  }
  float agg = a / L;
  sh[w][c] = agg; __syncthreads();
  float o1 = b_o1[c];
  #pragma unroll
  for (int k4=0;k4<16;k4++){
    float4 hv = *(const float4*)&sh[w][k4*4];
    o1 += d4(hv, *(const float4*)&w_o1[c*64+k4*4]);
  }
  o1 = leaky(o1);
  __syncthreads();
  sh[w][c] = o1; __syncthreads();
  float o2 = b_o2[c];
  #pragma unroll
  for (int k4=0;k4<16;k4++){
    float4 hv = *(const float4*)&sh[w][k4*4];
    o2 += d4(hv, *(const float4*)&w_o2[c*64+k4*4]);
  }
  o2 = leaky(o2);
  o2b[i*64+c] = o2;

  float s = o2, qq = o2*o2;
  s += __shfl_xor(s,1);  qq += __shfl_xor(qq,1);
  s += __shfl_xor(s,2);  qq += __shfl_xor(qq,2);
  s += __shfl_xor(s,4);  qq += __shfl_xor(qq,4);
  s += __shfl_xor(s,8);  qq += __shfl_xor(qq,8);
  if ((c&15)==0){ int g=c>>4; sred[w][g]=s; sred[w][4+g]=qq; }
  __syncthreads();
  if (t<8) bstat2[blockIdx.x*8+t] = sred[0][t]+sred[1][t]+sred[2][t]+sred[3][t];
}

// ---------------- K5: reduce out-stats, final group-norm + residual ----------------
__global__ __launch_bounds__(256) void k_out(
  const float* __restrict__ o2b, const float* __restrict__ bstat2,
  const float* __restrict__ g_out, const float* __restrict__ be_out,
  const float* __restrict__ feat, const float* __restrict__ w_res, const float* __restrict__ b_res,
  float* __restrict__ out)
{
  __shared__ float sp[64];
  __shared__ float sst[8];
  int t = threadIdx.x, w = t>>6, c = t&63;
  int i = blockIdx.x*4 + w;
  if (t<64){ int g=t&7; float s=0.f;
    for (int m=t>>3; m<400; m+=8) s += bstat2[m*8+g];
    sp[t]=s; }
  __syncthreads();
  if (t<8){ float s=0.f;
    #pragma unroll
    for (int q=0;q<8;q++) s += sp[q*8+t];
    sst[t]=s; }
  __syncthreads();
  int g = c>>4;
  const float inv = 1.f/25600.f;
  float mu = sst[g]*inv;
  float var = sst[4+g]*inv - mu*mu;
  float rs = rsqrtf(var + 1e-5f);
  float on = (o2b[i*64+c]-mu)*rs*g_out[c] + be_out[c];
  const float4* f4 = (const float4*)(feat + i*16);
  const float4* wr = (const float4*)(w_res + c*16);
  float res = b_res[c] + d4(f4[0],wr[0]) + d4(f4[1],wr[1]) + d4(f4[2],wr[2]) + d4(f4[3],wr[3]);
  out[i*64+c] = on + res;
}

extern "C" void kernel_launch(void* const* d_in, const int* in_sizes, int n_in,
                              void* d_out, int out_size, void* d_ws, size_t ws_size,
                              hipStream_t stream) {
  const float* points  = (const float*)d_in[0];
  const float* nuv     = (const float*)d_in[1];
  const float* feat    = (const float*)d_in[2];
  const float* w_in1   = (const float*)d_in[3];
  const float* b_in1   = (const float*)d_in[4];
  const float* w_in2   = (const float*)d_in[5];
  const float* b_in2   = (const float*)d_in[6];
  const float* g_in    = (const float*)d_in[7];
  const float* be_in   = (const float*)d_in[8];
  const float* wq      = (const float*)d_in[9];
  const float* bq      = (const float*)d_in[10];
  const float* wk      = (const float*)d_in[11];
  const float* bk      = (const float*)d_in[12];
  const float* wv      = (const float*)d_in[13];
  const float* bv      = (const float*)d_in[14];
  const float* conv_w1 = (const float*)d_in[15];
  const float* conv_b1 = (const float*)d_in[16];
  const float* conv_w2 = (const float*)d_in[17];
  const float* conv_b2 = (const float*)d_in[18];
  const float* rbf_ls  = (const float*)d_in[19];
  const float* rbf_a   = (const float*)d_in[20];
  const float* rbf_b   = (const float*)d_in[21];
  const float* rbf_c   = (const float*)d_in[22];
  const float* w_o1    = (const float*)d_in[23];
  const float* b_o1    = (const float*)d_in[24];
  const float* w_o2    = (const float*)d_in[25];
  const float* b_o2    = (const float*)d_in[26];
  const float* g_out   = (const float*)d_in[27];
  const float* be_out  = (const float*)d_in[28];
  const float* w_res   = (const float*)d_in[29];
  const float* b_res   = (const float*)d_in[30];

  float* ws     = (float*)d_ws;
  float* h2f    = ws;                 // 102400
  float* Qb     = ws + 102400;        // 102400
  float* Kb     = ws + 204800;        // 102400
  float* Vb     = ws + 307200;        // 102400
  float* bstat1 = ws + 409600;        // 3200
  float* bstat2 = ws + 412800;        // 3200
  float* wpk    = ws + 416000;        // 320
  float* part   = ws + 416320;        // 10*1600*72 = 1152000
  float* o2b    = ws + 1568320;       // 102400
  float* out    = (float*)d_out;

  k_in<<<400, 256, 0, stream>>>(feat, w_in1, b_in1, w_in2, b_in2,
                                conv_w1, conv_b1, conv_w2, rbf_a, rbf_b, rbf_ls, rbf_c,
                                h2f, bstat1, wpk);
  k_qkv<<<400, 256, 0, stream>>>(h2f, bstat1, g_in, be_in, wq, bq, wk, bk, wv, bv, Qb, Kb, Vb);
  k_pair<<<1000, 256, 0, stream>>>(Qb, Kb, Vb, points, nuv, conv_w1, wpk, conv_b2, part);
  k_agg<<<400, 256, 0, stream>>>(part, w_o1, b_o1, w_o2, b_o2, o2b, bstat2);
  k_out<<<400, 256, 0, stream>>>(o2b, bstat2, g_out, be_out, feat, w_res, b_res, out);
}

// Round 6
// 248.125 us; speedup vs baseline: 1.3877x; 1.0207x over previous
//
#include <hip/hip_runtime.h>

typedef __fp16 h2 __attribute__((ext_vector_type(2)));
typedef unsigned int u32;
typedef unsigned short u16;

#define NPTS 1600
#define NCHUNK 10
#define CHUNKJ 160
#define TILE 32
// softmax scale * log2e folded into Q
#define QS (0.35355339059327373f*1.4426950408889634f)
// 1/(sqrt(2)*6)
#define PSCALE 0.11785113019775793f
#define LOG2E 1.4426950408889634f

__device__ __forceinline__ float leaky(float x){ return x >= 0.f ? x : 0.2f*x; }
__device__ __forceinline__ float d4(float4 a, float4 b){ return a.x*b.x + a.y*b.y + a.z*b.z + a.w*b.w; }
__device__ __forceinline__ u32 pkn(float a, float b){ h2 v; v[0]=(__fp16)a; v[1]=(__fp16)b; return __builtin_bit_cast(u32,v); }
__device__ __forceinline__ h2 u2h(u32 u){ return __builtin_bit_cast(h2,u); }
__device__ __forceinline__ float dot2(h2 a, h2 b, float c){ return __builtin_amdgcn_fdot2(a,b,c,false); }
__device__ __forceinline__ u32 rfl(u32 x){ return (u32)__builtin_amdgcn_readfirstlane((int)x); }

// ---------------- K1: input MLP + group stats partials + weight packing ----------------
__global__ __launch_bounds__(256) void k_in(
    const float* __restrict__ feat, const float* __restrict__ w1, const float* __restrict__ b1,
    const float* __restrict__ w2, const float* __restrict__ b2,
    const float* __restrict__ conv_w1, const float* __restrict__ conv_b1,
    const float* __restrict__ conv_w2,
    const float* __restrict__ rbf_a, const float* __restrict__ rbf_b,
    const float* __restrict__ rbf_ls, const float* __restrict__ rbf_c,
    float* __restrict__ h2out, float* __restrict__ bstat1, float* __restrict__ wpk)
{
  __shared__ float sh[4][64];
  __shared__ float sred[4][8];
  int t = threadIdx.x, w = t>>6, c = t&63;
  int i = blockIdx.x*4 + w;

  if (blockIdx.x == 0) {
    u32* wp = (u32*)wpk;
    { // w2 packed f16: 64 rows x 4 u32
      int row = t>>2, q = t&3;
      wp[32 + row*4 + q] = pkn(conv_w2[row*8+2*q], conv_w2[row*8+2*q+1]);
    }
    if (t < 32) { // folded rbf weights: wrg = conv_w1[:,4:8] @ rbf_a
      int cc = t>>2, kq = t&3;
      float a0=0.f, a1=0.f;
      #pragma unroll
      for (int p=0;p<4;p++){ a0 += conv_w1[cc*8+4+p]*rbf_a[p*8+2*kq]; a1 += conv_w1[cc*8+4+p]*rbf_a[p*8+2*kq+1]; }
      wp[cc*4+kq] = pkn(a0,a1);
    } else if (t < 40) { // b1' = conv_b1 + conv_w1[:,4:8] @ rbf_b
      int cc = t-32; float s = conv_b1[cc];
      #pragma unroll
      for (int p=0;p<4;p++) s += conv_w1[cc*8+4+p]*rbf_b[p];
      wpk[288+cc] = s;
    } else if (t == 40) { // rbf quadratic-in-dd coefficients (uniform centers)
      float sig = fmaxf(expf(rbf_ls[0]), 1e-6f);
      float m = -LOG2E/(2.f*sig*sig);
      float c0 = rbf_c[0];
      float dl = rbf_c[1] - rbf_c[0];
      wpk[296] = c0;
      wpk[297] = m;
      wpk[298] = -2.f*m*dl;   // C2
      wpk[299] = m*dl*dl;     // A1
    }
  }

  const float4* f4 = (const float4*)(feat + i*16);
  float4 f0=f4[0], f1v=f4[1], f2v=f4[2], f3v=f4[3];
  const float4* w1r = (const float4*)(w1 + c*16);
  float h1 = b1[c] + d4(f0,w1r[0]) + d4(f1v,w1r[1]) + d4(f2v,w1r[2]) + d4(f3v,w1r[3]);
  h1 = leaky(h1);
  sh[w][c] = h1;
  __syncthreads();
  float hh = b2[c];
  #pragma unroll
  for (int k4=0;k4<16;k4++){
    float4 hv = *(const float4*)&sh[w][k4*4];
    hh += d4(hv, *(const float4*)&w2[c*64 + k4*4]);
  }
  hh = leaky(hh);
  h2out[i*64+c] = hh;

  float s = hh, qq = hh*hh;
  s += __shfl_xor(s,1);  qq += __shfl_xor(qq,1);
  s += __shfl_xor(s,2);  qq += __shfl_xor(qq,2);
  s += __shfl_xor(s,4);  qq += __shfl_xor(qq,4);
  s += __shfl_xor(s,8);  qq += __shfl_xor(qq,8);
  if ((c&15)==0){ int g=c>>4; sred[w][g]=s; sred[w][4+g]=qq; }
  __syncthreads();
  if (t<8) bstat1[blockIdx.x*8+t] = sred[0][t]+sred[1][t]+sred[2][t]+sred[3][t];
}

// ---------------- K2: reduce stats, group-norm, packed Q/K/V + PN ----------------
__global__ __launch_bounds__(256) void k_qkv(
  const float* __restrict__ h2b, const float* __restrict__ bstat1,
  const float* __restrict__ g_in, const float* __restrict__ be_in,
  const float* __restrict__ wq, const float* __restrict__ bq,
  const float* __restrict__ wk, const float* __restrict__ bk,
  const float* __restrict__ wv, const float* __restrict__ bv,
  const float* __restrict__ pts, const float* __restrict__ nuv,
  u32* __restrict__ Q16, u32* __restrict__ K16, u32* __restrict__ V16,
  float* __restrict__ PN)
{
  __shared__ float sh[4][64];
  __shared__ float sp[64];
  __shared__ float sst[8];
  int t=threadIdx.x, w=t>>6, c=t&63;
  int i = blockIdx.x*4 + w;
  if (t<64){ int g=t&7; float s=0.f;
    for (int m=t>>3; m<400; m+=8) s += bstat1[m*8+g];
    sp[t]=s; }
  __syncthreads();
  if (t<8){ float s=0.f;
    #pragma unroll
    for (int q=0;q<8;q++) s += sp[q*8+t];
    sst[t]=s; }
  __syncthreads();
  int g = c>>4;
  const float inv = 1.f/25600.f;
  float mu = sst[g]*inv;
  float var = sst[4+g]*inv - mu*mu;
  float rs = rsqrtf(var + 1e-5f);
  float hn = (h2b[i*64+c]-mu)*rs*g_in[c] + be_in[c];
  sh[w][c] = hn;
  __syncthreads();
  float q=bq[c], k=bk[c], v=bv[c];
  #pragma unroll
  for (int k4=0;k4<16;k4++){
    float4 hv = *(const float4*)&sh[w][k4*4];
    q += d4(hv, *(const float4*)&wq[c*64+k4*4]);
    k += d4(hv, *(const float4*)&wk[c*64+k4*4]);
    v += d4(hv, *(const float4*)&wv[c*64+k4*4]);
  }
  // packed outputs
  u16* Q16u = (u16*)Q16;
  u16* K16u = (u16*)K16;
  u16* V16u = (u16*)V16;
  __fp16 qh = (__fp16)(q*QS);
  __fp16 kh = (__fp16)k;
  __fp16 vh = (__fp16)v;
  Q16u[i*64 + c] = __builtin_bit_cast(u16, qh);
  K16u[i*64 + c] = __builtin_bit_cast(u16, kh);
  int pr = ((i>>5)<<4) + (i&15);   // pair row: (j, j+16) within 32-group
  int hf = (i>>4)&1;
  V16u[(pr*64 + c)*2 + hf] = __builtin_bit_cast(u16, vh);
  if (c < 6){
    float pv = (c<3) ? pts[i*3+c]*PSCALE : nuv[i*9+(c-3)];
    PN[i*8+c] = pv;
  } else if (c < 8) PN[i*8+c] = 0.f;
}

// ---------------- K3: all-pairs kernel (packed f16 dot2 everywhere) ----------------
__global__ __launch_bounds__(256) void k_pair(
  const u32* __restrict__ Q16, const u32* __restrict__ K16, const u32* __restrict__ V16,
  const float* __restrict__ PN, const float* __restrict__ nuv,
  const float* __restrict__ w1, const float* __restrict__ wpk,
  const float* __restrict__ b2g, float* __restrict__ part)
{
  __shared__ __align__(16) float SM[4608];
  u32*   sQ16 = (u32*)SM;          // [16][36]
  u32*   sK16 = (u32*)SM + 576;    // [32][36]
  u32*   sV16 = (u32*)SM + 1728;   // [16][68] paired f16 (rows jl / jl+16)
  float* sPN  = SM + 2816;         // [32][8]
  u32*   sWX  = (u32*)SM + 3072;   // [16][20]
  float* sRed = SM;                // [4][16][72] alias (post-loop only)

  int t = threadIdx.x;
  int r = t & 15, jl = t >> 4;
  int bx = blockIdx.x;
  int rb = bx % 100, jc = bx / 100;
  int I0 = rb*16, J0 = jc*CHUNKJ;
  int i = I0 + r;

  if (t < 128) { // stage Q16 tile: 16x32 u32
    int qrow = t>>3, qq4 = (t&7)<<2;
    *(uint4*)&sQ16[qrow*36+qq4] = *(const uint4*)&Q16[(I0+qrow)*32+qq4];
  }
  if (t < 128) { // wx[c][:] = conv_w1[c,0:3] @ nuv[i] ; last = conv_w1[c,3]
    int r2 = t>>3, cc = t&7, ib = (I0+r2)*9;
    float a0=w1[cc*8], a1=w1[cc*8+1], a2=w1[cc*8+2];
    float x = a0*nuv[ib+0] + a1*nuv[ib+3] + a2*nuv[ib+6];
    float y = a0*nuv[ib+1] + a1*nuv[ib+4] + a2*nuv[ib+7];
    float z = a0*nuv[ib+2] + a1*nuv[ib+5] + a2*nuv[ib+8];
    sWX[r2*20+cc*2+0] = pkn(x,y);
    sWX[r2*20+cc*2+1] = pkn(z, w1[cc*8+3]);
  }
  __syncthreads();
  u32 wxp[16];
  #pragma unroll
  for (int q2=0;q2<4;q2++) *(uint4*)&wxp[q2*4] = *(const uint4*)&sWX[r*20+q2*4];

  const u32* wp = (const u32*)wpk;
  h2 wr[8][4];
  #pragma unroll
  for (int cc=0;cc<8;cc++)
    #pragma unroll
    for (int q2=0;q2<4;q2++) wr[cc][q2] = u2h(rfl(wp[cc*4+q2]));
  const u32* w2p = wp + 32;
  const float* b1p = wpk + 288;
  float c0  = wpk[296];
  float mco = wpk[297];
  float C2  = wpk[298];
  float A1  = wpk[299];

  float4 pni0 = *(const float4*)&PN[i*8];
  float4 pni1 = *(const float4*)&PN[i*8+4];
  float pix = pni0.x, piy = pni0.y, piz = pni0.z;
  float nix = pni0.w, niy = pni1.x, niz = pni1.y;

  float acc[64];
  #pragma unroll
  for (int o=0;o<64;o++) acc[o] = 0.f;
  float lh[8];
  #pragma unroll
  for (int h=0;h<8;h++) lh[h] = 0.f;

  #pragma unroll 1
  for (int tb=0; tb<CHUNKJ; tb+=TILE) {
    int jbase = J0 + tb;
    __syncthreads();
    { // stage K16: 32 rows x 32 u32 (1 uint4/thread)
      int krow = t>>3, kq = (t&7)<<2;
      *(uint4*)&sK16[krow*36+kq] = *(const uint4*)&K16[(jbase+krow)*32 + kq];
    }
    { // stage V16: 16 pair-rows x 64 u32 (1 uint4/thread)
      int vrow = t>>4, vq = (t&15)<<2;
      *(uint4*)&sV16[vrow*68+vq] = *(const uint4*)&V16[((jbase>>1)+vrow)*64 + vq];
    }
    if (t < 64) { // stage PN: 32 rows x 8 f32
      int prow = t>>1, ph = (t&1)<<2;
      *(float4*)&sPN[prow*8+ph] = *(const float4*)&PN[(jbase+prow)*8+ph];
    }
    __syncthreads();

    h2 F1p[2][4];
    float Wv[2];
    #pragma unroll
    for (int jj=0;jj<2;jj++) {
      int jloc = jl + (jj<<4);
      float4 a0 = *(const float4*)&sPN[jloc*8];
      float4 a1 = *(const float4*)&sPN[jloc*8+4];
      float dx = a0.x-pix, dy = a0.y-piy, dz = a0.z-piz;
      float ndot = nix*a0.w + niy*a1.x + niz*a1.y;
      float d2r = dx*dx + dy*dy + dz*dz;
      float wf = 2.f - ndot;
      float d2 = d2r*wf*wf;
      float tp = fmaf(d2, 0.3333333333333333f, 1.f);
      Wv[jj] = __builtin_amdgcn_rcpf(tp*tp*tp);     // (1+d2/3)^-3
      float dd = __builtin_amdgcn_sqrtf(d2);
      float g0 = dd - c0;
      float s2 = mco*g0*g0;
      float uu = C2*g0;
      float R[8];
      #pragma unroll
      for (int k=0;k<8;k++){
        float kf = (float)k, k2f = (float)(k*k);
        R[k] = __builtin_amdgcn_exp2f(fmaf(kf, uu, fmaf(k2f, A1, s2)));
      }
      h2 xv0; xv0[0]=(__fp16)dx; xv0[1]=(__fp16)dy;
      h2 xv1; xv1[0]=(__fp16)dz; xv1[1]=(__fp16)ndot;
      h2 r01=__builtin_amdgcn_cvt_pkrtz(R[0],R[1]);
      h2 r23=__builtin_amdgcn_cvt_pkrtz(R[2],R[3]);
      h2 r45=__builtin_amdgcn_cvt_pkrtz(R[4],R[5]);
      h2 r67=__builtin_amdgcn_cvt_pkrtz(R[6],R[7]);
      float F1f[8];
      #pragma unroll
      for (int cc=0;cc<8;cc++){
        float f = dot2(r67, wr[cc][3], b1p[cc]);
        f = dot2(r45, wr[cc][2], f);
        f = dot2(r23, wr[cc][1], f);
        f = dot2(r01, wr[cc][0], f);
        f = dot2(u2h(wxp[cc*2+1]), xv1, f);
        f = dot2(u2h(wxp[cc*2+0]), xv0, f);
        F1f[cc] = fmaxf(f, 0.f);
      }
      F1p[jj][0]=__builtin_amdgcn_cvt_pkrtz(F1f[0],F1f[1]);
      F1p[jj][1]=__builtin_amdgcn_cvt_pkrtz(F1f[2],F1f[3]);
      F1p[jj][2]=__builtin_amdgcn_cvt_pkrtz(F1f[4],F1f[5]);
      F1p[jj][3]=__builtin_amdgcn_cvt_pkrtz(F1f[6],F1f[7]);
    }
    h2 Wvp = __builtin_amdgcn_cvt_pkrtz(Wv[0], Wv[1]);

    #pragma unroll
    for (int h=0;h<8;h++) {
      uint4 qh = *(const uint4*)&sQ16[r*36 + (h<<2)];
      uint4 kA = *(const uint4*)&sK16[jl*36 + (h<<2)];
      uint4 kB = *(const uint4*)&sK16[(jl+16)*36 + (h<<2)];
      float S0 = dot2(u2h(qh.x),u2h(kA.x), dot2(u2h(qh.y),u2h(kA.y),
                 dot2(u2h(qh.z),u2h(kA.z), dot2(u2h(qh.w),u2h(kA.w), 0.f))));
      float S1 = dot2(u2h(qh.x),u2h(kB.x), dot2(u2h(qh.y),u2h(kB.y),
                 dot2(u2h(qh.z),u2h(kB.z), dot2(u2h(qh.w),u2h(kB.w), 0.f))));
      float e0 = __builtin_amdgcn_exp2f(S0);
      float e1 = __builtin_amdgcn_exp2f(S1);
      lh[h] += e0 + e1;
      h2 ewp = __builtin_amdgcn_cvt_pkrtz(e0,e1) * Wvp;
      uint4 vpA = *(const uint4*)&sV16[jl*68 + h*8];
      uint4 vpB = *(const uint4*)&sV16[jl*68 + h*8 + 4];
      u32 vparr[8] = {vpA.x,vpA.y,vpA.z,vpA.w,vpB.x,vpB.y,vpB.z,vpB.w};
      #pragma unroll
      for (int cc=0;cc<8;cc++){
        int rw = h*8+cc;
        h2 w0=u2h(w2p[rw*4+0]), w1h=u2h(w2p[rw*4+1]), w2h=u2h(w2p[rw*4+2]), w3h=u2h(w2p[rw*4+3]);
        float b2v = b2g[rw];
        float fh0 = dot2(F1p[0][0],w0, dot2(F1p[0][1],w1h, dot2(F1p[0][2],w2h, dot2(F1p[0][3],w3h, b2v))));
        float fh1 = dot2(F1p[1][0],w0, dot2(F1p[1][1],w1h, dot2(F1p[1][2],w2h, dot2(F1p[1][3],w3h, b2v))));
        h2 fhp = __builtin_amdgcn_cvt_pkrtz(fmaxf(fh0,0.f), fmaxf(fh1,0.f));
        h2 ev = u2h(vparr[cc]) * ewp;
        acc[rw] = dot2(fhp, ev, acc[rw]);
      }
    }
  }

  #pragma unroll
  for (int o=0;o<64;o++){ acc[o] += __shfl_xor(acc[o],16); acc[o] += __shfl_xor(acc[o],32); }
  #pragma unroll
  for (int h=0;h<8;h++){ lh[h] += __shfl_xor(lh[h],16); lh[h] += __shfl_xor(lh[h],32); }
  __syncthreads();
  int wv = t >> 6, lane = t & 63;
  if (lane < 16) {
    #pragma unroll
    for (int o=0;o<64;o++) sRed[(wv*16+lane)*72+o] = acc[o];
    #pragma unroll
    for (int h=0;h<8;h++) sRed[(wv*16+lane)*72+64+h] = lh[h];
  }
  __syncthreads();
  for (int v2 = t; v2 < 16*72; v2 += 256) {
    int rr = v2/72, o = v2 - rr*72;
    part[(jc*NPTS + I0 + rr)*72 + o] =
      sRed[(0*16+rr)*72+o] + sRed[(1*16+rr)*72+o] + sRed[(2*16+rr)*72+o] + sRed[(3*16+rr)*72+o];
  }
}

// ---------------- K4: merge chunk partials, divide, output MLP, out-stat partials ----------------
__global__ __launch_bounds__(256) void k_agg(
  const float* __restrict__ part, const float* __restrict__ w_o1, const float* __restrict__ b_o1,
  const float* __restrict__ w_o2, const float* __restrict__ b_o2,
  float* __restrict__ o2b, float* __restrict__ bstat2)
{
  __shared__ float sh[4][64];
  __shared__ float sred[4][8];
  int t = threadIdx.x, w = t>>6, c = t&63;
  int i = blockIdx.x*4 + w;
  int h = c>>3;
  float a = 0.f, L = 0.f;
  #pragma unroll
  for (int jc=0;jc<NCHUNK;jc++){
    const float* p = part + (jc*NPTS + i)*72;
    a += p[c]; L += p[64+h];
  }
  float agg = a / L;
  sh[w][c] = agg; __syncthreads();
  float o1 = b_o1[c];
  #pragma unroll
  for (int k4=0;k4<16;k4++){
    float4 hv = *(const float4*)&sh[w][k4*4];
    o1 += d4(hv, *(const float4*)&w_o1[c*64+k4*4]);
  }
  o1 = leaky(o1);
  __syncthreads();
  sh[w][c] = o1; __syncthreads();
  float o2 = b_o2[c];
  #pragma unroll
  for (int k4=0;k4<16;k4++){
    float4 hv = *(const float4*)&sh[w][k4*4];
    o2 += d4(hv, *(const float4*)&w_o2[c*64+k4*4]);
  }
  o2 = leaky(o2);
  o2b[i*64+c] = o2;

  float s = o2, qq = o2*o2;
  s += __shfl_xor(s,1);  qq += __shfl_xor(qq,1);
  s += __shfl_xor(s,2);  qq += __shfl_xor(qq,2);
  s += __shfl_xor(s,4);  qq += __shfl_xor(qq,4);
  s += __shfl_xor(s,8);  qq += __shfl_xor(qq,8);
  if ((c&15)==0){ int g=c>>4; sred[w][g]=s; sred[w][4+g]=qq; }
  __syncthreads();
  if (t<8) bstat2[blockIdx.x*8+t] = sred[0][t]+sred[1][t]+sred[2][t]+sred[3][t];
}

// ---------------- K5: reduce out-stats, final group-norm + residual ----------------
__global__ __launch_bounds__(256) void k_out(
  const float* __restrict__ o2b, const float* __restrict__ bstat2,
  const float* __restrict__ g_out, const float* __restrict__ be_out,
  const float* __restrict__ feat, const float* __restrict__ w_res, const float* __restrict__ b_res,
  float* __restrict__ out)
{
  __shared__ float sp[64];
  __shared__ float sst[8];
  int t = threadIdx.x, w = t>>6, c = t&63;
  int i = blockIdx.x*4 + w;
  if (t<64){ int g=t&7; float s=0.f;
    for (int m=t>>3; m<400; m+=8) s += bstat2[m*8+g];
    sp[t]=s; }
  __syncthreads();
  if (t<8){ float s=0.f;
    #pragma unroll
    for (int q=0;q<8;q++) s += sp[q*8+t];
    sst[t]=s; }
  __syncthreads();
  int g = c>>4;
  const float inv = 1.f/25600.f;
  float mu = sst[g]*inv;
  float var = sst[4+g]*inv - mu*mu;
  float rs = rsqrtf(var + 1e-5f);
  float on = (o2b[i*64+c]-mu)*rs*g_out[c] + be_out[c];
  const float4* f4 = (const float4*)(feat + i*16);
  const float4* wr = (const float4*)(w_res + c*16);
  float res = b_res[c] + d4(f4[0],wr[0]) + d4(f4[1],wr[1]) + d4(f4[2],wr[2]) + d4(f4[3],wr[3]);
  out[i*64+c] = on + res;
}

extern "C" void kernel_launch(void* const* d_in, const int* in_sizes, int n_in,
                              void* d_out, int out_size, void* d_ws, size_t ws_size,
                              hipStream_t stream) {
  const float* points  = (const float*)d_in[0];
  const float* nuv     = (const float*)d_in[1];
  const float* feat    = (const float*)d_in[2];
  const float* w_in1   = (const float*)d_in[3];
  const float* b_in1   = (const float*)d_in[4];
  const float* w_in2   = (const float*)d_in[5];
  const float* b_in2   = (const float*)d_in[6];
  const float* g_in    = (const float*)d_in[7];
  const float* be_in   = (const float*)d_in[8];
  const float* wq      = (const float*)d_in[9];
  const float* bq      = (const float*)d_in[10];
  const float* wk      = (const float*)d_in[11];
  const float* bk      = (const float*)d_in[12];
  const float* wv      = (const float*)d_in[13];
  const float* bv      = (const float*)d_in[14];
  const float* conv_w1 = (const float*)d_in[15];
  const float* conv_b1 = (const float*)d_in[16];
  const float* conv_w2 = (const float*)d_in[17];
  const float* conv_b2 = (const float*)d_in[18];
  const float* rbf_ls  = (const float*)d_in[19];
  const float* rbf_a   = (const float*)d_in[20];
  const float* rbf_b   = (const float*)d_in[21];
  const float* rbf_c   = (const float*)d_in[22];
  const float* w_o1    = (const float*)d_in[23];
  const float* b_o1    = (const float*)d_in[24];
  const float* w_o2    = (const float*)d_in[25];
  const float* b_o2    = (const float*)d_in[26];
  const float* g_out   = (const float*)d_in[27];
  const float* be_out  = (const float*)d_in[28];
  const float* w_res   = (const float*)d_in[29];
  const float* b_res   = (const float*)d_in[30];

  float* ws     = (float*)d_ws;
  float* h2f    = ws;                 // 102400
  u32*   Q16    = (u32*)(ws + 102400);// 51200 u32
  u32*   K16    = (u32*)(ws + 153600);// 51200 u32
  u32*   V16    = (u32*)(ws + 204800);// 51200 u32
  float* PN     = ws + 256000;        // 12800
  float* bstat1 = ws + 268800;        // 3200
  float* bstat2 = ws + 272000;        // 3200
  float* wpk    = ws + 275200;        // 320
  float* part   = ws + 275520;        // 1152000
  float* o2b    = ws + 1427520;       // 102400
  float* out    = (float*)d_out;

  k_in<<<400, 256, 0, stream>>>(feat, w_in1, b_in1, w_in2, b_in2,
                                conv_w1, conv_b1, conv_w2, rbf_a, rbf_b, rbf_ls, rbf_c,
                                h2f, bstat1, wpk);
  k_qkv<<<400, 256, 0, stream>>>(h2f, bstat1, g_in, be_in, wq, bq, wk, bk, wv, bv,
                                 points, nuv, Q16, K16, V16, PN);
  k_pair<<<1000, 256, 0, stream>>>(Q16, K16, V16, PN, nuv, conv_w1, wpk, conv_b2, part);
  k_agg<<<400, 256, 0, stream>>>(part, w_o1, b_o1, w_o2, b_o2, o2b, bstat2);
  k_out<<<400, 256, 0, stream>>>(o2b, bstat2, g_out, be_out, feat, w_res, b_res, out);
}

// Round 7
// 237.756 us; speedup vs baseline: 1.4482x; 1.0436x over previous
//
#include <hip/hip_runtime.h>

typedef __fp16 h2 __attribute__((ext_vector_type(2)));
typedef unsigned int u32;
typedef unsigned short u16;

#define NPTS 1600
#define NCHUNK 10
#define CHUNKJ 160
#define TILE 32
// softmax scale * log2e folded into Q
#define QS (0.35355339059327373f*1.4426950408889634f)
// 1/(sqrt(2)*6)
#define PSCALE 0.11785113019775793f
#define LOG2E 1.4426950408889634f

__device__ __forceinline__ float leaky(float x){ return x >= 0.f ? x : 0.2f*x; }
__device__ __forceinline__ float d4(float4 a, float4 b){ return a.x*b.x + a.y*b.y + a.z*b.z + a.w*b.w; }
__device__ __forceinline__ u32 pkn(float a, float b){ h2 v; v[0]=(__fp16)a; v[1]=(__fp16)b; return __builtin_bit_cast(u32,v); }
__device__ __forceinline__ h2 u2h(u32 u){ return __builtin_bit_cast(h2,u); }
__device__ __forceinline__ float dot2(h2 a, h2 b, float c){ return __builtin_amdgcn_fdot2(a,b,c,false); }
__device__ __forceinline__ u32 rfl(u32 x){ return (u32)__builtin_amdgcn_readfirstlane((int)x); }

// ---------------- K1: input MLP + group stats partials + weight packing ----------------
__global__ __launch_bounds__(256) void k_in(
    const float* __restrict__ feat, const float* __restrict__ w1, const float* __restrict__ b1,
    const float* __restrict__ w2, const float* __restrict__ b2,
    const float* __restrict__ conv_w1, const float* __restrict__ conv_b1,
    const float* __restrict__ conv_w2,
    const float* __restrict__ rbf_a, const float* __restrict__ rbf_b,
    const float* __restrict__ rbf_ls, const float* __restrict__ rbf_c,
    float* __restrict__ h2out, float* __restrict__ bstat1, float* __restrict__ wpk)
{
  __shared__ float sh[4][64];
  __shared__ float sred[4][8];
  int t = threadIdx.x, w = t>>6, c = t&63;
  int i = blockIdx.x*4 + w;

  if (blockIdx.x == 0) {
    u32* wp = (u32*)wpk;
    { // w2 packed f16: 64 rows x 4 u32
      int row = t>>2, q = t&3;
      wp[32 + row*4 + q] = pkn(conv_w2[row*8+2*q], conv_w2[row*8+2*q+1]);
    }
    if (t < 32) { // folded rbf weights: wrg = conv_w1[:,4:8] @ rbf_a
      int cc = t>>2, kq = t&3;
      float a0=0.f, a1=0.f;
      #pragma unroll
      for (int p=0;p<4;p++){ a0 += conv_w1[cc*8+4+p]*rbf_a[p*8+2*kq]; a1 += conv_w1[cc*8+4+p]*rbf_a[p*8+2*kq+1]; }
      wp[cc*4+kq] = pkn(a0,a1);
    } else if (t < 40) { // b1' = conv_b1 + conv_w1[:,4:8] @ rbf_b
      int cc = t-32; float s = conv_b1[cc];
      #pragma unroll
      for (int p=0;p<4;p++) s += conv_w1[cc*8+4+p]*rbf_b[p];
      wpk[288+cc] = s;
    } else if (t == 40) { // rbf quadratic-in-dd coefficients (uniform centers)
      float sig = fmaxf(expf(rbf_ls[0]), 1e-6f);
      float m = -LOG2E/(2.f*sig*sig);
      float c0 = rbf_c[0];
      float dl = rbf_c[1] - rbf_c[0];
      wpk[296] = c0;
      wpk[297] = m;
      wpk[298] = -2.f*m*dl;   // C2
      wpk[299] = m*dl*dl;     // A1
    }
  }

  const float4* f4 = (const float4*)(feat + i*16);
  float4 f0=f4[0], f1v=f4[1], f2v=f4[2], f3v=f4[3];
  const float4* w1r = (const float4*)(w1 + c*16);
  float h1 = b1[c] + d4(f0,w1r[0]) + d4(f1v,w1r[1]) + d4(f2v,w1r[2]) + d4(f3v,w1r[3]);
  h1 = leaky(h1);
  sh[w][c] = h1;
  __syncthreads();
  float hh = b2[c];
  #pragma unroll
  for (int k4=0;k4<16;k4++){
    float4 hv = *(const float4*)&sh[w][k4*4];
    hh += d4(hv, *(const float4*)&w2[c*64 + k4*4]);
  }
  hh = leaky(hh);
  h2out[i*64+c] = hh;

  float s = hh, qq = hh*hh;
  s += __shfl_xor(s,1);  qq += __shfl_xor(qq,1);
  s += __shfl_xor(s,2);  qq += __shfl_xor(qq,2);
  s += __shfl_xor(s,4);  qq += __shfl_xor(qq,4);
  s += __shfl_xor(s,8);  qq += __shfl_xor(qq,8);
  if ((c&15)==0){ int g=c>>4; sred[w][g]=s; sred[w][4+g]=qq; }
  __syncthreads();
  if (t<8) bstat1[blockIdx.x*8+t] = sred[0][t]+sred[1][t]+sred[2][t]+sred[3][t];
}

// ---------------- K2: reduce stats, group-norm, packed Q/K/V + PN ----------------
__global__ __launch_bounds__(256) void k_qkv(
  const float* __restrict__ h2b, const float* __restrict__ bstat1,
  const float* __restrict__ g_in, const float* __restrict__ be_in,
  const float* __restrict__ wq, const float* __restrict__ bq,
  const float* __restrict__ wk, const float* __restrict__ bk,
  const float* __restrict__ wv, const float* __restrict__ bv,
  const float* __restrict__ pts, const float* __restrict__ nuv,
  u32* __restrict__ Q16, u32* __restrict__ K16, u32* __restrict__ V16,
  float* __restrict__ PN)
{
  __shared__ float sh[4][64];
  __shared__ float sp[64];
  __shared__ float sst[8];
  int t=threadIdx.x, w=t>>6, c=t&63;
  int i = blockIdx.x*4 + w;
  if (t<64){ int g=t&7; float s=0.f;
    for (int m=t>>3; m<400; m+=8) s += bstat1[m*8+g];
    sp[t]=s; }
  __syncthreads();
  if (t<8){ float s=0.f;
    #pragma unroll
    for (int q=0;q<8;q++) s += sp[q*8+t];
    sst[t]=s; }
  __syncthreads();
  int g = c>>4;
  const float inv = 1.f/25600.f;
  float mu = sst[g]*inv;
  float var = sst[4+g]*inv - mu*mu;
  float rs = rsqrtf(var + 1e-5f);
  float hn = (h2b[i*64+c]-mu)*rs*g_in[c] + be_in[c];
  sh[w][c] = hn;
  __syncthreads();
  float q=bq[c], k=bk[c], v=bv[c];
  #pragma unroll
  for (int k4=0;k4<16;k4++){
    float4 hv = *(const float4*)&sh[w][k4*4];
    q += d4(hv, *(const float4*)&wq[c*64+k4*4]);
    k += d4(hv, *(const float4*)&wk[c*64+k4*4]);
    v += d4(hv, *(const float4*)&wv[c*64+k4*4]);
  }
  // packed outputs
  u16* Q16u = (u16*)Q16;
  u16* K16u = (u16*)K16;
  u16* V16u = (u16*)V16;
  __fp16 qh = (__fp16)(q*QS);
  __fp16 kh = (__fp16)k;
  __fp16 vh = (__fp16)v;
  Q16u[i*64 + c] = __builtin_bit_cast(u16, qh);
  K16u[i*64 + c] = __builtin_bit_cast(u16, kh);
  int pr = ((i>>5)<<4) + (i&15);   // pair row: (j, j+16) within 32-group
  int hf = (i>>4)&1;
  V16u[(pr*64 + c)*2 + hf] = __builtin_bit_cast(u16, vh);
  if (c < 6){
    float pv = (c<3) ? pts[i*3+c]*PSCALE : nuv[i*9+(c-3)];
    PN[i*8+c] = pv;
  } else if (c < 8) PN[i*8+c] = 0.f;
}

// ---------------- K3: all-pairs kernel — barrier-free main loop, K/V/PN direct from L2 ----------------
__global__ __launch_bounds__(256) void k_pair(
  const u32* __restrict__ Q16, const u32* __restrict__ K16, const u32* __restrict__ V16,
  const float* __restrict__ PN, const float* __restrict__ nuv,
  const float* __restrict__ w1, const float* __restrict__ wpk,
  const float* __restrict__ b2g, float* __restrict__ part)
{
  __shared__ __align__(16) float SM[4608];
  u32*   sQ16 = (u32*)SM;          // [16][36]
  u32*   sWX  = (u32*)SM + 576;    // [16][20]
  float* sRed = SM;                // [4][16][72] alias (post-loop only, behind barrier)

  int t = threadIdx.x;
  int r = t & 15, jl = t >> 4;
  int bx = blockIdx.x;
  int rb = bx % 100, jc = bx / 100;
  int I0 = rb*16, J0 = jc*CHUNKJ;
  int i = I0 + r;

  if (t < 128) { // stage Q16 tile: 16x32 u32
    int qrow = t>>3, qq4 = (t&7)<<2;
    *(uint4*)&sQ16[qrow*36+qq4] = *(const uint4*)&Q16[(I0+qrow)*32+qq4];
  }
  if (t < 128) { // wx[c][:] = conv_w1[c,0:3] @ nuv[i] ; last = conv_w1[c,3]
    int r2 = t>>3, cc = t&7, ib = (I0+r2)*9;
    float a0=w1[cc*8], a1=w1[cc*8+1], a2=w1[cc*8+2];
    float x = a0*nuv[ib+0] + a1*nuv[ib+3] + a2*nuv[ib+6];
    float y = a0*nuv[ib+1] + a1*nuv[ib+4] + a2*nuv[ib+7];
    float z = a0*nuv[ib+2] + a1*nuv[ib+5] + a2*nuv[ib+8];
    sWX[r2*20+cc*2+0] = pkn(x,y);
    sWX[r2*20+cc*2+1] = pkn(z, w1[cc*8+3]);
  }
  __syncthreads();
  u32 wxp[16];
  #pragma unroll
  for (int q2=0;q2<4;q2++) *(uint4*)&wxp[q2*4] = *(const uint4*)&sWX[r*20+q2*4];

  const u32* wp = (const u32*)wpk;
  h2 wr[8][4];
  #pragma unroll
  for (int cc=0;cc<8;cc++)
    #pragma unroll
    for (int q2=0;q2<4;q2++) wr[cc][q2] = u2h(rfl(wp[cc*4+q2]));
  const u32* w2p = wp + 32;
  const float* b1p = wpk + 288;
  float c0  = wpk[296];
  float mco = wpk[297];
  float C2  = wpk[298];
  float A1  = wpk[299];

  float4 pni0 = *(const float4*)&PN[i*8];
  float4 pni1 = *(const float4*)&PN[i*8+4];
  float pix = pni0.x, piy = pni0.y, piz = pni0.z;
  float nix = pni0.w, niy = pni1.x, niz = pni1.y;

  float acc[64];
  #pragma unroll
  for (int o=0;o<64;o++) acc[o] = 0.f;
  float lh[8];
  #pragma unroll
  for (int h=0;h<8;h++) lh[h] = 0.f;

  #pragma unroll 1
  for (int tb=0; tb<CHUNKJ; tb+=TILE) {
    int jbase = J0 + tb;
    int jA = jbase + jl;
    int jB = jA + 16;

    h2 F1p[2][4];
    float Wv[2];
    #pragma unroll
    for (int jj=0;jj<2;jj++) {
      int j = jj ? jB : jA;
      float4 a0 = *(const float4*)&PN[j*8];
      float4 a1 = *(const float4*)&PN[j*8+4];
      float dx = a0.x-pix, dy = a0.y-piy, dz = a0.z-piz;
      float ndot = nix*a0.w + niy*a1.x + niz*a1.y;
      float d2r = dx*dx + dy*dy + dz*dz;
      float wf = 2.f - ndot;
      float d2 = d2r*wf*wf;
      float tp = fmaf(d2, 0.3333333333333333f, 1.f);
      Wv[jj] = __builtin_amdgcn_rcpf(tp*tp*tp);     // (1+d2/3)^-3
      float dd = __builtin_amdgcn_sqrtf(d2);
      float g0 = dd - c0;
      float s2 = mco*g0*g0;
      float uu = C2*g0;
      float R[8];
      #pragma unroll
      for (int k=0;k<8;k++){
        float kf = (float)k, k2f = (float)(k*k);
        R[k] = __builtin_amdgcn_exp2f(fmaf(kf, uu, fmaf(k2f, A1, s2)));
      }
      h2 xv0; xv0[0]=(__fp16)dx; xv0[1]=(__fp16)dy;
      h2 xv1; xv1[0]=(__fp16)dz; xv1[1]=(__fp16)ndot;
      h2 r01=__builtin_amdgcn_cvt_pkrtz(R[0],R[1]);
      h2 r23=__builtin_amdgcn_cvt_pkrtz(R[2],R[3]);
      h2 r45=__builtin_amdgcn_cvt_pkrtz(R[4],R[5]);
      h2 r67=__builtin_amdgcn_cvt_pkrtz(R[6],R[7]);
      float F1f[8];
      #pragma unroll
      for (int cc=0;cc<8;cc++){
        float f = dot2(r67, wr[cc][3], b1p[cc]);
        f = dot2(r45, wr[cc][2], f);
        f = dot2(r23, wr[cc][1], f);
        f = dot2(r01, wr[cc][0], f);
        f = dot2(u2h(wxp[cc*2+1]), xv1, f);
        f = dot2(u2h(wxp[cc*2+0]), xv0, f);
        F1f[cc] = fmaxf(f, 0.f);
      }
      F1p[jj][0]=__builtin_amdgcn_cvt_pkrtz(F1f[0],F1f[1]);
      F1p[jj][1]=__builtin_amdgcn_cvt_pkrtz(F1f[2],F1f[3]);
      F1p[jj][2]=__builtin_amdgcn_cvt_pkrtz(F1f[4],F1f[5]);
      F1p[jj][3]=__builtin_amdgcn_cvt_pkrtz(F1f[6],F1f[7]);
    }
    h2 Wvp = __builtin_amdgcn_cvt_pkrtz(Wv[0], Wv[1]);

    const u32* kArow = &K16[jA*32];
    const u32* kBrow = &K16[jB*32];
    const u32* vrow  = &V16[(((u32)jbase>>1)+jl)*64];

    #pragma unroll
    for (int h=0;h<8;h++) {
      uint4 qh = *(const uint4*)&sQ16[r*36 + (h<<2)];
      uint4 kA = *(const uint4*)&kArow[h<<2];
      uint4 kB = *(const uint4*)&kBrow[h<<2];
      float S0 = dot2(u2h(qh.x),u2h(kA.x), dot2(u2h(qh.y),u2h(kA.y),
                 dot2(u2h(qh.z),u2h(kA.z), dot2(u2h(qh.w),u2h(kA.w), 0.f))));
      float S1 = dot2(u2h(qh.x),u2h(kB.x), dot2(u2h(qh.y),u2h(kB.y),
                 dot2(u2h(qh.z),u2h(kB.z), dot2(u2h(qh.w),u2h(kB.w), 0.f))));
      float e0 = __builtin_amdgcn_exp2f(S0);
      float e1 = __builtin_amdgcn_exp2f(S1);
      lh[h] += e0 + e1;
      h2 ewp = __builtin_amdgcn_cvt_pkrtz(e0,e1) * Wvp;
      uint4 vpA = *(const uint4*)&vrow[h*8];
      uint4 vpB = *(const uint4*)&vrow[h*8+4];
      u32 vparr[8] = {vpA.x,vpA.y,vpA.z,vpA.w,vpB.x,vpB.y,vpB.z,vpB.w};
      #pragma unroll
      for (int cc=0;cc<8;cc++){
        int rw = h*8+cc;
        h2 w0=u2h(w2p[rw*4+0]), w1h=u2h(w2p[rw*4+1]), w2h=u2h(w2p[rw*4+2]), w3h=u2h(w2p[rw*4+3]);
        float b2v = b2g[rw];
        float fh0 = dot2(F1p[0][0],w0, dot2(F1p[0][1],w1h, dot2(F1p[0][2],w2h, dot2(F1p[0][3],w3h, b2v))));
        float fh1 = dot2(F1p[1][0],w0, dot2(F1p[1][1],w1h, dot2(F1p[1][2],w2h, dot2(F1p[1][3],w3h, b2v))));
        h2 fhp = __builtin_amdgcn_cvt_pkrtz(fmaxf(fh0,0.f), fmaxf(fh1,0.f));
        h2 ev = u2h(vparr[cc]) * ewp;
        acc[rw] = dot2(fhp, ev, acc[rw]);
      }
    }
  }

  #pragma unroll
  for (int o=0;o<64;o++){ acc[o] += __shfl_xor(acc[o],16); acc[o] += __shfl_xor(acc[o],32); }
  #pragma unroll
  for (int h=0;h<8;h++){ lh[h] += __shfl_xor(lh[h],16); lh[h] += __shfl_xor(lh[h],32); }
  __syncthreads();   // protects sQ16/sWX region before sRed alias reuse
  int wv = t >> 6, lane = t & 63;
  if (lane < 16) {
    #pragma unroll
    for (int o=0;o<64;o++) sRed[(wv*16+lane)*72+o] = acc[o];
    #pragma unroll
    for (int h=0;h<8;h++) sRed[(wv*16+lane)*72+64+h] = lh[h];
  }
  __syncthreads();
  for (int v2 = t; v2 < 16*72; v2 += 256) {
    int rr = v2/72, o = v2 - rr*72;
    part[(jc*NPTS + I0 + rr)*72 + o] =
      sRed[(0*16+rr)*72+o] + sRed[(1*16+rr)*72+o] + sRed[(2*16+rr)*72+o] + sRed[(3*16+rr)*72+o];
  }
}

// ---------------- K4: merge chunk partials, divide, output MLP, out-stat partials ----------------
__global__ __launch_bounds__(256) void k_agg(
  const float* __restrict__ part, const float* __restrict__ w_o1, const float* __restrict__ b_o1,
  const float* __restrict__ w_o2, const float* __restrict__ b_o2,
  float* __restrict__ o2b, float* __restrict__ bstat2)
{
  __shared__ float sh[4][64];
  __shared__ float sred[4][8];
  int t = threadIdx.x, w = t>>6, c = t&63;
  int i = blockIdx.x*4 + w;
  int h = c>>3;
  float a = 0.f, L = 0.f;
  #pragma unroll
  for (int jc=0;jc<NCHUNK;jc++){
    const float* p = part + (jc*NPTS + i)*72;
    a += p[c]; L += p[64+h];
  }
  float agg = a / L;
  sh[w][c] = agg; __syncthreads();
  float o1 = b_o1[c];
  #pragma unroll
  for (int k4=0;k4<16;k4++){
    float4 hv = *(const float4*)&sh[w][k4*4];
    o1 += d4(hv, *(const float4*)&w_o1[c*64+k4*4]);
  }
  o1 = leaky(o1);
  __syncthreads();
  sh[w][c] = o1; __syncthreads();
  float o2 = b_o2[c];
  #pragma unroll
  for (int k4=0;k4<16;k4++){
    float4 hv = *(const float4*)&sh[w][k4*4];
    o2 += d4(hv, *(const float4*)&w_o2[c*64+k4*4]);
  }
  o2 = leaky(o2);
  o2b[i*64+c] = o2;

  float s = o2, qq = o2*o2;
  s += __shfl_xor(s,1);  qq += __shfl_xor(qq,1);
  s += __shfl_xor(s,2);  qq += __shfl_xor(qq,2);
  s += __shfl_xor(s,4);  qq += __shfl_xor(qq,4);
  s += __shfl_xor(s,8);  qq += __shfl_xor(qq,8);
  if ((c&15)==0){ int g=c>>4; sred[w][g]=s; sred[w][4+g]=qq; }
  __syncthreads();
  if (t<8) bstat2[blockIdx.x*8+t] = sred[0][t]+sred[1][t]+sred[2][t]+sred[3][t];
}

// ---------------- K5: reduce out-stats, final group-norm + residual ----------------
__global__ __launch_bounds__(256) void k_out(
  const float* __restrict__ o2b, const float* __restrict__ bstat2,
  const float* __restrict__ g_out, const float* __restrict__ be_out,
  const float* __restrict__ feat, const float* __restrict__ w_res, const float* __restrict__ b_res,
  float* __restrict__ out)
{
  __shared__ float sp[64];
  __shared__ float sst[8];
  int t = threadIdx.x, w = t>>6, c = t&63;
  int i = blockIdx.x*4 + w;
  if (t<64){ int g=t&7; float s=0.f;
    for (int m=t>>3; m<400; m+=8) s += bstat2[m*8+g];
    sp[t]=s; }
  __syncthreads();
  if (t<8){ float s=0.f;
    #pragma unroll
    for (int q=0;q<8;q++) s += sp[q*8+t];
    sst[t]=s; }
  __syncthreads();
  int g = c>>4;
  const float inv = 1.f/25600.f;
  float mu = sst[g]*inv;
  float var = sst[4+g]*inv - mu*mu;
  float rs = rsqrtf(var + 1e-5f);
  float on = (o2b[i*64+c]-mu)*rs*g_out[c] + be_out[c];
  const float4* f4 = (const float4*)(feat + i*16);
  const float4* wr = (const float4*)(w_res + c*16);
  float res = b_res[c] + d4(f4[0],wr[0]) + d4(f4[1],wr[1]) + d4(f4[2],wr[2]) + d4(f4[3],wr[3]);
  out[i*64+c] = on + res;
}

extern "C" void kernel_launch(void* const* d_in, const int* in_sizes, int n_in,
                              void* d_out, int out_size, void* d_ws, size_t ws_size,
                              hipStream_t stream) {
  const float* points  = (const float*)d_in[0];
  const float* nuv     = (const float*)d_in[1];
  const float* feat    = (const float*)d_in[2];
  const float* w_in1   = (const float*)d_in[3];
  const float* b_in1   = (const float*)d_in[4];
  const float* w_in2   = (const float*)d_in[5];
  const float* b_in2   = (const float*)d_in[6];
  const float* g_in    = (const float*)d_in[7];
  const float* be_in   = (const float*)d_in[8];
  const float* wq      = (const float*)d_in[9];
  const float* bq      = (const float*)d_in[10];
  const float* wk      = (const float*)d_in[11];
  const float* bk      = (const float*)d_in[12];
  const float* wv      = (const float*)d_in[13];
  const float* bv      = (const float*)d_in[14];
  const float* conv_w1 = (const float*)d_in[15];
  const float* conv_b1 = (const float*)d_in[16];
  const float* conv_w2 = (const float*)d_in[17];
  const float* conv_b2 = (const float*)d_in[18];
  const float* rbf_ls  = (const float*)d_in[19];
  const float* rbf_a   = (const float*)d_in[20];
  const float* rbf_b   = (const float*)d_in[21];
  const float* rbf_c   = (const float*)d_in[22];
  const float* w_o1    = (const float*)d_in[23];
  const float* b_o1    = (const float*)d_in[24];
  const float* w_o2    = (const float*)d_in[25];
  const float* b_o2    = (const float*)d_in[26];
  const float* g_out   = (const float*)d_in[27];
  const float* be_out  = (const float*)d_in[28];
  const float* w_res   = (const float*)d_in[29];
  const float* b_res   = (const float*)d_in[30];

  float* ws     = (float*)d_ws;
  float* h2f    = ws;                 // 102400
  u32*   Q16    = (u32*)(ws + 102400);// 51200 u32
  u32*   K16    = (u32*)(ws + 153600);// 51200 u32
  u32*   V16    = (u32*)(ws + 204800);// 51200 u32
  float* PN     = ws + 256000;        // 12800
  float* bstat1 = ws + 268800;        // 3200
  float* bstat2 = ws + 272000;        // 3200
  float* wpk    = ws + 275200;        // 320
  float* part   = ws + 275520;        // 1152000
  float* o2b    = ws + 1427520;       // 102400
  float* out    = (float*)d_out;

  k_in<<<400, 256, 0, stream>>>(feat, w_in1, b_in1, w_in2, b_in2,
                                conv_w1, conv_b1, conv_w2, rbf_a, rbf_b, rbf_ls, rbf_c,
                                h2f, bstat1, wpk);
  k_qkv<<<400, 256, 0, stream>>>(h2f, bstat1, g_in, be_in, wq, bq, wk, bk, wv, bv,
                                 points, nuv, Q16, K16, V16, PN);
  k_pair<<<1000, 256, 0, stream>>>(Q16, K16, V16, PN, nuv, conv_w1, wpk, conv_b2, part);
  k_agg<<<400, 256, 0, stream>>>(part, w_o1, b_o1, w_o2, b_o2, o2b, bstat2);
  k_out<<<400, 256, 0, stream>>>(o2b, bstat2, g_out, be_out, feat, w_res, b_res, out);
}